// Round 4
// baseline (1564.926 us; speedup 1.0000x reference)
//
#include <hip/hip_runtime.h>
#include <stdint.h>

// Problem constants (fixed by the reference)
#define M_DIM 8192    // 4*2048 rows of x
#define K_DIM 4096    // shared dim
#define N_DIM 11008   // output features

#define BM 128
#define BN 128
#define BK 64

// Harness dtype mapping (deduced from rounds 1-3 failure signatures):
//   x: float32 (fp16 upcast), w: int32 (int8 widened), s: float32, out: float32.

typedef __attribute__((ext_vector_type(8))) _Float16 half8;   // MFMA A/B fragment
typedef __attribute__((ext_vector_type(4))) _Float16 half4;
typedef __attribute__((ext_vector_type(4))) float floatx4;

// ---------------------------------------------------------------------------
// Kernel 1: dequantize q4_0 -> fp16 deq[N_DIM][K_DIM] in workspace.
// w row r (64 ints): msb nibbles -> deq[n=r/32][128*(r%32)+j], scale s[2r]
//                    lsb nibbles -> +64, scale s[2r+1].
// fp32 mul + single rounding to fp16 == reference's fp16 multiply (bit-exact).
// ---------------------------------------------------------------------------
__global__ __launch_bounds__(256) void dequant_q40(const int* __restrict__ w,
                                                   const float* __restrict__ s,
                                                   _Float16* __restrict__ deq) {
    int t = blockIdx.x * 256 + threadIdx.x;      // 352256*8 threads
    int r = t >> 3;                               // w row
    int j = (t & 7) * 8;                          // int offset in row
    const int* wp = w + (size_t)r * 64 + j;
    int4 p0 = *(const int4*)(wp);
    int4 p1 = *(const int4*)(wp + 4);
    float sm = s[2 * r];
    float sl = s[2 * r + 1];
    int n = r >> 5, u = r & 31;
    _Float16* dm = deq + (size_t)n * K_DIM + u * 128 + j;
    int v[8] = {p0.x, p0.y, p0.z, p0.w, p1.x, p1.y, p1.z, p1.w};
    half8 vm, vl;
#pragma unroll
    for (int i = 0; i < 8; ++i) {
        int b = v[i];                             // original int8 value, widened
        vm[i] = (_Float16)((float)(b >> 4) * sm);          // arithmetic msb
        vl[i] = (_Float16)((float)((b << 28) >> 28) * sl); // sign-extended lsb
    }
    *(half8*)dm = vm;
    *(half8*)(dm + 64) = vl;
}

// ---------------------------------------------------------------------------
// Kernel 2: gemm_bt, explicit staging. C[M][N] = A[M][K] * deq[N][K]^T.
// A fp32 (converted to fp16 during staging), B fp16 (prepass), C fp32.
// 128x128 tile, BK=64, 4 waves (2x2), wave = 64x64 via 4x4 mfma 16x16x32 f16.
// ---------------------------------------------------------------------------
__global__ __launch_bounds__(256, 2) void gemm_f16_bt(const float* __restrict__ A,
                                                      const _Float16* __restrict__ B,
                                                      float* __restrict__ C) {
    __shared__ _Float16 As[BM * BK];   // [128][64] row-major fp16
    __shared__ _Float16 Bs[BN * BK];

    const int tid  = threadIdx.x;
    const int lane = tid & 63;
    const int wave = tid >> 6;
    const int wm = (wave >> 1) * 64;
    const int wn = (wave & 1) * 64;
    const int m0 = blockIdx.y * BM;
    const int n0 = blockIdx.x * BN;

    floatx4 acc[4][4] = {};
    const int lrow = lane & 15;        // fragment row index (m or n)
    const int quad = lane >> 4;        // k sub-offset selector

    for (int kk = 0; kk < K_DIM; kk += BK) {
        // ---- A tile: 128x64 fp32 = 8192 floats; 8 x (256 thr x float4)
        float4 av[8];
#pragma unroll
        for (int i = 0; i < 8; ++i) {
            int flat = i * 256 + tid;          // [0,2048)
            int row = flat >> 4;               // 16 threads/row, 4 floats each
            int col = (flat & 15) * 4;
            av[i] = *(const float4*)(A + (size_t)(m0 + row) * K_DIM + kk + col);
        }
        // ---- B tile: 128x64 fp16 = 8192 halfs; 4 x (256 thr x half8)
        half8 bv[4];
#pragma unroll
        for (int i = 0; i < 4; ++i) {
            int flat = i * 256 + tid;          // [0,1024)
            int row = flat >> 3;               // 8 threads/row, 8 halfs each
            int col = (flat & 7) * 8;
            bv[i] = *(const half8*)(B + (size_t)(n0 + row) * K_DIM + kk + col);
        }
        __syncthreads();   // prior iteration's LDS reads done before overwrite
#pragma unroll
        for (int i = 0; i < 8; ++i) {
            int flat = i * 256 + tid;
            int row = flat >> 4;
            int col = (flat & 15) * 4;
            half4 a16;
            a16[0] = (_Float16)av[i].x;        // lossless: x values are fp16-exact
            a16[1] = (_Float16)av[i].y;
            a16[2] = (_Float16)av[i].z;
            a16[3] = (_Float16)av[i].w;
            *(half4*)(As + row * BK + col) = a16;
        }
#pragma unroll
        for (int i = 0; i < 4; ++i) {
            int flat = i * 256 + tid;
            *(half8*)(Bs + (size_t)flat * 8) = bv[i];
        }
        __syncthreads();   // tiles visible to all waves

        // ---- compute: 2 k-iters of 32, 16 MFMAs each
#pragma unroll
        for (int ks = 0; ks < BK; ks += 32) {
            int koff = ks + quad * 8;
            half8 af[4], bf[4];
#pragma unroll
            for (int im = 0; im < 4; ++im)
                af[im] = *(const half8*)(As + (wm + im * 16 + lrow) * BK + koff);
#pragma unroll
            for (int in_ = 0; in_ < 4; ++in_)
                bf[in_] = *(const half8*)(Bs + (wn + in_ * 16 + lrow) * BK + koff);
#pragma unroll
            for (int im = 0; im < 4; ++im)
#pragma unroll
                for (int in_ = 0; in_ < 4; ++in_)
                    acc[im][in_] = __builtin_amdgcn_mfma_f32_16x16x32_f16(
                        af[im], bf[in_], acc[im][in_], 0, 0, 0);
        }
    }

    // ---- epilogue: C/D layout col=lane&15, row=(lane>>4)*4+reg; fp32 stores
#pragma unroll
    for (int im = 0; im < 4; ++im) {
#pragma unroll
        for (int in_ = 0; in_ < 4; ++in_) {
            int col = n0 + wn + in_ * 16 + lrow;
#pragma unroll
            for (int r = 0; r < 4; ++r) {
                int row = m0 + wm + im * 16 + quad * 4 + r;
                C[(size_t)row * N_DIM + col] = acc[im][in_][r];
            }
        }
    }
}

// ---------------------------------------------------------------------------
// Fallback: fused dequant-in-GEMM (only if ws too small for the deq prepass).
// ---------------------------------------------------------------------------
__global__ __launch_bounds__(256, 2) void gemm_fused(const float* __restrict__ A,
                                                     const int* __restrict__ W,
                                                     const float* __restrict__ S,
                                                     float* __restrict__ C) {
    __shared__ _Float16 As[BM * BK];
    __shared__ _Float16 Bs[BN * BK];

    const int tid  = threadIdx.x;
    const int lane = tid & 63;
    const int wave = tid >> 6;
    const int wm = (wave >> 1) * 64;
    const int wn = (wave & 1) * 64;
    const int m0 = blockIdx.y * BM;
    const int n0 = blockIdx.x * BN;

    floatx4 acc[4][4] = {};
    const int lrow = lane & 15;
    const int quad = lane >> 4;

    const int nn = tid >> 1;           // n-row handled by this thread (pairwise)
    const int bh = (tid & 1) * 32;     // which half of the 64-wide k-group

    for (int kk = 0; kk < K_DIM; kk += BK) {
        float4 av[8];
#pragma unroll
        for (int i = 0; i < 8; ++i) {
            int flat = i * 256 + tid;
            int row = flat >> 4;
            int col = (flat & 15) * 4;
            av[i] = *(const float4*)(A + (size_t)(m0 + row) * K_DIM + kk + col);
        }
        // B: dequant 32 ints -> 32 fp16 per thread, covering Bs[nn][bh..bh+31]
        int t64 = kk >> 6;             // scale-group index along k
        int u = t64 >> 1;              // w sub-row
        const int* wr = W + ((size_t)(n0 + nn) * 32 + u) * 64 + bh;
        float sc = S[(size_t)(n0 + nn) * 64 + t64];
        bool sel_lsb = (t64 & 1);
        half8 bq[4];
#pragma unroll
        for (int i8 = 0; i8 < 4; ++i8) {
            int4 pa = *(const int4*)(wr + i8 * 8);
            int4 pb = *(const int4*)(wr + i8 * 8 + 4);
            int vv[8] = {pa.x, pa.y, pa.z, pa.w, pb.x, pb.y, pb.z, pb.w};
#pragma unroll
            for (int q = 0; q < 8; ++q) {
                int b = vv[q];
                int qq = sel_lsb ? ((b << 28) >> 28) : (b >> 4);
                bq[i8][q] = (_Float16)((float)qq * sc);
            }
        }
        __syncthreads();
#pragma unroll
        for (int i = 0; i < 8; ++i) {
            int flat = i * 256 + tid;
            int row = flat >> 4;
            int col = (flat & 15) * 4;
            half4 a16;
            a16[0] = (_Float16)av[i].x;
            a16[1] = (_Float16)av[i].y;
            a16[2] = (_Float16)av[i].z;
            a16[3] = (_Float16)av[i].w;
            *(half4*)(As + row * BK + col) = a16;
        }
#pragma unroll
        for (int i8 = 0; i8 < 4; ++i8)
            *(half8*)(Bs + nn * BK + bh + i8 * 8) = bq[i8];
        __syncthreads();

#pragma unroll
        for (int ks = 0; ks < BK; ks += 32) {
            int koff = ks + quad * 8;
            half8 af[4], bf[4];
#pragma unroll
            for (int im = 0; im < 4; ++im)
                af[im] = *(const half8*)(As + (wm + im * 16 + lrow) * BK + koff);
#pragma unroll
            for (int in_ = 0; in_ < 4; ++in_)
                bf[in_] = *(const half8*)(Bs + (wn + in_ * 16 + lrow) * BK + koff);
#pragma unroll
            for (int im = 0; im < 4; ++im)
#pragma unroll
                for (int in_ = 0; in_ < 4; ++in_)
                    acc[im][in_] = __builtin_amdgcn_mfma_f32_16x16x32_f16(
                        af[im], bf[in_], acc[im][in_], 0, 0, 0);
        }
    }

#pragma unroll
    for (int im = 0; im < 4; ++im) {
#pragma unroll
        for (int in_ = 0; in_ < 4; ++in_) {
            int col = n0 + wn + in_ * 16 + lrow;
#pragma unroll
            for (int r = 0; r < 4; ++r) {
                int row = m0 + wm + im * 16 + quad * 4 + r;
                C[(size_t)row * N_DIM + col] = acc[im][in_][r];
            }
        }
    }
}

extern "C" void kernel_launch(void* const* d_in, const int* in_sizes, int n_in,
                              void* d_out, int out_size, void* d_ws, size_t ws_size,
                              hipStream_t stream) {
    const float* x = (const float*)d_in[0];   // fp16 upcast to fp32 by harness
    const int*   w = (const int*)d_in[1];     // int8 widened to int32
    const float* s = (const float*)d_in[2];   // fp16 upcast to fp32
    float*     out = (float*)d_out;           // fp32

    const size_t deq_bytes = (size_t)N_DIM * K_DIM * sizeof(_Float16); // 90.2 MB
    dim3 grid(N_DIM / BN, M_DIM / BM);   // 86 x 64 = 5504 blocks

    if (ws_size >= deq_bytes) {
        _Float16* deq = (_Float16*)d_ws;
        dequant_q40<<<11008, 256, 0, stream>>>(w, s, deq);
        gemm_f16_bt<<<grid, 256, 0, stream>>>(x, deq, out);
    } else {
        gemm_fused<<<grid, 256, 0, stream>>>(x, w, s, out);
    }
}